// Round 2
// baseline (177.057 us; speedup 1.0000x reference)
//
#include <hip/hip_runtime.h>
#include <hip/hip_bf16.h>

typedef __hip_bfloat16 bf16;
typedef __attribute__((ext_vector_type(8))) short bf16x8;
typedef __attribute__((ext_vector_type(8))) _Float16 f16x8;
typedef __attribute__((ext_vector_type(4))) float f32x4;

constexpr int N_TOK = 2048;
constexpr int DIMM  = 1024;
constexpr int NH    = 16;
constexpr int HD    = 64;
constexpr int FM    = 64;
constexpr int NC    = 32;
constexpr int CS    = 64;

__device__ __forceinline__ float b2f(bf16 v) { return __bfloat162float(v); }
__device__ __forceinline__ unsigned short f2bfu(float v) {
  bf16 h = __float2bfloat16(v);
  return *reinterpret_cast<unsigned short*>(&h);
}
__device__ __forceinline__ unsigned short f2hu(float v) {
  _Float16 h = (_Float16)v;
  return *reinterpret_cast<unsigned short*>(&h);
}

__device__ __forceinline__ void gl_lds16(const void* g, short* l) {
  __builtin_amdgcn_global_load_lds(
      (const __attribute__((address_space(1))) void*)g,
      (__attribute__((address_space(3))) void*)l, 16, 0, 0);
}

__device__ __forceinline__ void split_pack_bf(const float4 v, uint2& ph, uint2& pl) {
  float f[4] = {v.x, v.y, v.z, v.w};
  unsigned short h[4], l[4];
  #pragma unroll
  for (int j = 0; j < 4; j++) {
    bf16 hb = __float2bfloat16(f[j]);
    h[j] = *reinterpret_cast<unsigned short*>(&hb);
    l[j] = f2bfu(f[j] - b2f(hb));
  }
  ph.x = (unsigned)h[0] | ((unsigned)h[1] << 16);
  ph.y = (unsigned)h[2] | ((unsigned)h[3] << 16);
  pl.x = (unsigned)l[0] | ((unsigned)l[1] << 16);
  pl.y = (unsigned)l[2] | ((unsigned)l[3] << 16);
}

// Fused conversions: x -> fp16; wq|wk|wv -> fp16 [3072][1024]; wo -> bf16.
__global__ __launch_bounds__(256) void cvt_all(
    const float4* __restrict__ x, const float4* __restrict__ wq,
    const float4* __restrict__ wk, const float4* __restrict__ wv,
    const float4* __restrict__ wo,
    _Float16* __restrict__ x16, _Float16* __restrict__ w16,
    bf16* __restrict__ wo_bf)
{
  int i = blockIdx.x * 256 + threadIdx.x;   // < 1572864
  if (i < 524288) {
    float4 v = x[i];
    uint2 p = { (unsigned)f2hu(v.x) | ((unsigned)f2hu(v.y) << 16),
                (unsigned)f2hu(v.z) | ((unsigned)f2hu(v.w) << 16) };
    reinterpret_cast<uint2*>(x16)[i] = p;
  } else if (i < 1310720) {
    int j = i - 524288;
    const float4* src = (j < 262144) ? wq : (j < 524288) ? wk : wv;
    int jj = (j < 262144) ? j : (j < 524288) ? j - 262144 : j - 524288;
    float4 v = src[jj];
    uint2 p = { (unsigned)f2hu(v.x) | ((unsigned)f2hu(v.y) << 16),
                (unsigned)f2hu(v.z) | ((unsigned)f2hu(v.w) << 16) };
    reinterpret_cast<uint2*>(w16)[j] = p;
  } else {
    int j = i - 1310720;
    float4 v = wo[j];
    uint2 p = { (unsigned)f2bfu(v.x) | ((unsigned)f2bfu(v.y) << 16),
                (unsigned)f2bfu(v.z) | ((unsigned)f2bfu(v.w) << 16) };
    reinterpret_cast<uint2*>(wo_bf)[j] = p;
  }
}

// Fused QKV projection + phi feature map.
// 512 threads = 8 waves. 128x128 tile, BK=64, split-K wave pairs: pair p = wv>>1
// owns 64x64 output sub-tile; ksub = wv&1 computes K-half [ksub*32, ksub*32+32)
// of each BK=64 slab -> per wave per iter 16 MFMA : 8 ds_read_b128 (2:1), 16
// barriers. XOR-swizzled LDS (linear dest for global_load_lds, pre-swizzled
// global source chunk cb ^= row&7, same XOR folded into the read address ->
// conflict-free ds_read_b128). Pair-sum via LDS fp32 scratch after main loop.
// Phi: 8 waves x 16 rows proj MFMA; norms exact fp32 in-wave shuffle.
__global__ __launch_bounds__(512, 4) void gemm_qkv_phi(
    const _Float16* __restrict__ A16, const _Float16* __restrict__ B16,
    const float* __restrict__ omega,
    bf16* __restrict__ phiq, bf16* __restrict__ phik, bf16* __restrict__ Cv)
{
  constexpr int K = 1024;
  __shared__ alignas(16) char smemRaw[65536];
  short* sA = (short*)smemRaw;          // [2][8192] fp16: [128][64] per buf
  short* sB = sA + 16384;               // [2][8192]

  const int tid = threadIdx.x, lane = tid & 63, wv = tid >> 6;  // wv 0..7
  const int colBase = blockIdx.x * 128, rowBase = blockIdx.y * 128;
  const int p = wv >> 1, ksub = wv & 1;
  const int waveRow = (p >> 1) * 64, waveCol = (p & 1) * 64;

  // staging: 4 x 16B chunks per thread per iter (A x2, B x2), swizzled source
  const int sRow = tid >> 3;                        // 0..63
  const int sCol = ((tid & 7) ^ (sRow & 7)) * 8;    // element offset in 64-wide slab
  const _Float16* gA0 = A16 + (size_t)(rowBase + sRow) * K + sCol;
  const _Float16* gA1 = gA0 + (size_t)64 * K;       // row+64: same xor (64%8==0)
  const _Float16* gB0 = B16 + (size_t)(colBase + sRow) * K + sCol;
  const _Float16* gB1 = gB0 + (size_t)64 * K;
  short* ldsA0 = sA + tid * 8;
  short* ldsA1 = sA + tid * 8 + 4096;
  short* ldsB0 = sB + tid * 8;
  short* ldsB1 = sB + tid * 8 + 4096;

  f32x4 acc[4][4];
  #pragma unroll
  for (int r = 0; r < 4; r++)
    #pragma unroll
    for (int c = 0; c < 4; c++) acc[r][c] = (f32x4){0.f, 0.f, 0.f, 0.f};

  const int frow = lane & 15, quad = lane >> 4, fk = quad * 8;
  const int xorOff = (((ksub << 2) + quad) ^ (frow & 7)) * 8;   // shorts
  const int nIter = K / 64;   // 16

  gl_lds16(gA0, ldsA0); gl_lds16(gA1, ldsA1);
  gl_lds16(gB0, ldsB0); gl_lds16(gB1, ldsB1);

  int buf = 0;
  for (int it = 0; it < nIter; it++) {
    __syncthreads();
    if (it + 1 < nIter) {
      const size_t kb = (size_t)(it + 1) * 64;
      const int nb = (buf ^ 1) * 8192;
      gl_lds16(gA0 + kb, ldsA0 + nb); gl_lds16(gA1 + kb, ldsA1 + nb);
      gl_lds16(gB0 + kb, ldsB0 + nb); gl_lds16(gB1 + kb, ldsB1 + nb);
    }
    const int bo = buf * 8192;
    f16x8 a[4], b[4];
    #pragma unroll
    for (int r = 0; r < 4; r++)
      a[r] = *reinterpret_cast<const f16x8*>(&sA[bo + (waveRow + r * 16 + frow) * 64 + xorOff]);
    #pragma unroll
    for (int c = 0; c < 4; c++)
      b[c] = *reinterpret_cast<const f16x8*>(&sB[bo + (waveCol + c * 16 + frow) * 64 + xorOff]);
    #pragma unroll
    for (int r = 0; r < 4; r++)
      #pragma unroll
      for (int c = 0; c < 4; c++)
        acc[r][c] = __builtin_amdgcn_mfma_f32_16x16x32_f16(a[r], b[c], acc[r][c], 0, 0, 0);
    buf ^= 1;
  }

  // ---- split-K pair sum through LDS fp32 scratch (reuses whole 64 KB) ----
  __syncthreads();
  float* sAcc = (float*)smemRaw;        // [4][64][64] fp32, 16 KB per pair
  if (ksub) {
    float* dstS = sAcc + p * 4096;
    #pragma unroll
    for (int r = 0; r < 4; r++)
      #pragma unroll
      for (int c = 0; c < 4; c++)
        #pragma unroll
        for (int reg = 0; reg < 4; reg++)
          dstS[(r * 16 + quad * 4 + reg) * 64 + c * 16 + frow] = acc[r][c][reg];
  }
  __syncthreads();
  if (!ksub) {
    const float* srcS = sAcc + p * 4096;
    #pragma unroll
    for (int r = 0; r < 4; r++)
      #pragma unroll
      for (int c = 0; c < 4; c++)
        #pragma unroll
        for (int reg = 0; reg < 4; reg++)
          acc[r][c][reg] += srcS[(r * 16 + quad * 4 + reg) * 64 + c * 16 + frow];
  }
  __syncthreads();   // scratch consumed before union reuse

  if (colBase >= 2048) {
    if (!ksub) {
      #pragma unroll
      for (int r = 0; r < 4; r++)
        #pragma unroll
        for (int c = 0; c < 4; c++)
          #pragma unroll
          for (int reg = 0; reg < 4; reg++) {
            int row = rowBase + waveRow + r * 16 + quad * 4 + reg;
            int col = colBase - 2048 + waveCol + c * 16 + frow;
            Cv[(size_t)row * 1024 + col] = __float2bfloat16(acc[r][c][reg]);
          }
    }
    return;
  }

  // --- phi phase (q or k) --- LDS: sQ16 18432 + sO16 9216 + sNorm 1024 B
  constexpr int LD = 72;
  short* sQ16 = (short*)smemRaw;          // [128][72] fp16, one head at a time
  short* sO16 = sQ16 + 9216;              // [64][72] fp16
  float* sNorm = (float*)(sO16 + 4608);   // [2][128]

  const bool isQ = (colBase < 1024);
  const int hPairBase = (isQ ? colBase : (colBase - 1024)) >> 6;
  bf16* dstBase = isQ ? phiq : phik;
  const int headOwn = p & 1;              // which head this wave's cols cover
  const bool owner = (ksub == 0);

  // stage omega fp16 (8 floats/thread -> one 16B write)
  {
    int r = tid >> 3, cg = (tid & 7) * 8;
    const float* src = omega + r * 64 + cg;
    float4 v0 = *reinterpret_cast<const float4*>(src);
    float4 v1 = *reinterpret_cast<const float4*>(src + 4);
    uint4 pk = { (unsigned)f2hu(v0.x) | ((unsigned)f2hu(v0.y) << 16),
                 (unsigned)f2hu(v0.z) | ((unsigned)f2hu(v0.w) << 16),
                 (unsigned)f2hu(v1.x) | ((unsigned)f2hu(v1.y) << 16),
                 (unsigned)f2hu(v1.z) | ((unsigned)f2hu(v1.w) << 16) };
    *reinterpret_cast<uint4*>(&sO16[r * LD + cg]) = pk;
  }

  // per-row ||q||^2: owner wave holds the full 64-dim head row -> exact fp32
  if (owner) {
    #pragma unroll
    for (int r = 0; r < 4; r++)
      #pragma unroll
      for (int reg = 0; reg < 4; reg++) {
        float s = 0.f;
        #pragma unroll
        for (int c = 0; c < 4; c++) s += acc[r][c][reg] * acc[r][c][reg];
        s += __shfl_xor(s, 1); s += __shfl_xor(s, 2);
        s += __shfl_xor(s, 4); s += __shfl_xor(s, 8);
        if (frow == 0)
          sNorm[headOwn * 128 + waveRow + r * 16 + quad * 4 + reg] = s;
      }
  }

  #pragma unroll
  for (int hh = 0; hh < 2; hh++) {
    if (owner && headOwn == hh) {
      // stage this head's q tile as fp16 (two owner waves: rows 0-63 / 64-127)
      #pragma unroll
      for (int r = 0; r < 4; r++)
        #pragma unroll
        for (int c = 0; c < 4; c++)
          #pragma unroll
          for (int reg = 0; reg < 4; reg++) {
            int row = waveRow + r * 16 + quad * 4 + reg;
            int lc = c * 16 + frow;
            sQ16[row * LD + lc] = (short)f2hu(acc[r][c][reg]);
          }
    }
    __syncthreads();

    // proj = q . omega^T; wave wv does rows wv*16..+15
    f32x4 acc2[4];
    #pragma unroll
    for (int ct = 0; ct < 4; ct++) acc2[ct] = (f32x4){0.f, 0.f, 0.f, 0.f};
    #pragma unroll
    for (int ks = 0; ks < 64; ks += 32) {
      f16x8 a = *reinterpret_cast<const f16x8*>(&sQ16[(wv * 16 + frow) * LD + ks + fk]);
      #pragma unroll
      for (int ct = 0; ct < 4; ct++) {
        f16x8 b = *reinterpret_cast<const f16x8*>(&sO16[(ct * 16 + frow) * LD + ks + fk]);
        acc2[ct] = __builtin_amdgcn_mfma_f32_16x16x32_f16(a, b, acc2[ct], 0, 0, 0);
      }
    }
    // phi epilogue
    const int h = hPairBase + hh;
    #pragma unroll
    for (int ct = 0; ct < 4; ct++)
      #pragma unroll
      for (int reg = 0; reg < 4; reg++) {
        int row = wv * 16 + quad * 4 + reg;
        int m = ct * 16 + frow;
        float norm = 0.5f * sNorm[hh * 128 + row];
        float v = __expf(fminf(acc2[ct][reg] - norm, 80.f)) * 0.125f;
        dstBase[((size_t)h * N_TOK + rowBase + row) * FM + m] = __float2bfloat16(v);
      }
    __syncthreads();   // before next head overwrites sQ16
  }
}

// Output projection: bf16 NT GEMM + bias, fp32 out. Block 64x128, 512 threads
// = 8 waves (2x4, wave tile 32x32), dbuf LDS 24 KB. Grid (8,32)=256 blocks.
__global__ __launch_bounds__(512) void gemm_bf16_out(
    const bf16* __restrict__ A, const bf16* __restrict__ B,
    const float* __restrict__ bias, float* __restrict__ C)
{
  constexpr int K = 1024;
  __shared__ short sA[2][2048], sB[2][4096];
  const int tid = threadIdx.x, lane = tid & 63, wv = tid >> 6;
  const int rowBase = blockIdx.y * 64, colBase = blockIdx.x * 128;
  const int waveRow = (wv >> 2) * 32, waveCol = (wv & 3) * 32;
  const int stR = tid >> 2, stK = (tid & 3) * 8;
  const bf16* gA = A + (size_t)(rowBase + stR) * K + stK;   // valid for wv<4 only
  const bf16* gB = B + (size_t)(colBase + stR) * K + stK;
  const int ldsOff = wv * 512;

  f32x4 acc[2][2];
  #pragma unroll
  for (int r = 0; r < 2; r++)
    #pragma unroll
    for (int c = 0; c < 2; c++) acc[r][c] = (f32x4){0.f, 0.f, 0.f, 0.f};

  const int frow = lane & 15, fk = (lane >> 4) * 8;
  const int nIter = K / 32;

  if (wv < 4) gl_lds16(gA, &sA[0][ldsOff]);
  gl_lds16(gB, &sB[0][ldsOff]);

  int buf = 0;
  for (int it = 0; it < nIter; it++) {
    __syncthreads();
    if (it + 1 < nIter) {
      const size_t kb = (size_t)(it + 1) * 32;
      const int nb = buf ^ 1;
      if (wv < 4) gl_lds16(gA + kb, &sA[nb][ldsOff]);
      gl_lds16(gB + kb, &sB[nb][ldsOff]);
    }
    bf16x8 a[2], b[2];
    #pragma unroll
    for (int r = 0; r < 2; r++)
      a[r] = *reinterpret_cast<const bf16x8*>(&sA[buf][(waveRow + r * 16 + frow) * 32 + fk]);
    #pragma unroll
    for (int c = 0; c < 2; c++)
      b[c] = *reinterpret_cast<const bf16x8*>(&sB[buf][(waveCol + c * 16 + frow) * 32 + fk]);
    #pragma unroll
    for (int r = 0; r < 2; r++)
      #pragma unroll
      for (int c = 0; c < 2; c++)
        acc[r][c] = __builtin_amdgcn_mfma_f32_16x16x32_bf16(a[r], b[c], acc[r][c], 0, 0, 0);
    buf ^= 1;
  }

  #pragma unroll
  for (int r = 0; r < 2; r++)
    #pragma unroll
    for (int c = 0; c < 2; c++)
      #pragma unroll
      for (int reg = 0; reg < 4; reg++) {
        int row = rowBase + waveRow + r * 16 + (lane >> 4) * 4 + reg;
        int col = colBase + waveCol + c * 16 + (lane & 15);
        C[(size_t)row * 1024 + col] = acc[r][c][reg] + bias[col];
      }
}

// MFMA chunk sums: ckv_t[h][c][d][m] = sum_j v[j][d]*phik[j][m]; ck = col sums of phik.
__global__ __launch_bounds__(256) void chunk_sum(
    const bf16* __restrict__ phik, const bf16* __restrict__ vf,
    float* __restrict__ ckv_t, float* __restrict__ ck)
{
  constexpr int LD = 72;
  __shared__ short sVt[64 * LD], sPkt[64 * LD];
  __shared__ float sCp[64][4];
  const int c = blockIdx.x, h = blockIdx.y;
  const int tid = threadIdx.x, lane = tid & 63, wv = tid >> 6;

  {
    int j = tid >> 2, g = tid & 3;
    const bf16* vs = vf + (size_t)(c * CS + j) * DIMM + h * HD + g * 16;
    uint4 v0 = *reinterpret_cast<const uint4*>(vs);
    uint4 v1 = *reinterpret_cast<const uint4*>(vs + 8);
    const unsigned short* pv = (const unsigned short*)&v0;
    #pragma unroll
    for (int e = 0; e < 8; e++) sVt[(g * 16 + e) * LD + j] = (short)pv[e];
    pv = (const unsigned short*)&v1;
    #pragma unroll
    for (int e = 0; e < 8; e++) sVt[(g * 16 + 8 + e) * LD + j] = (short)pv[e];

    const bf16* ks = phik + ((size_t)h * N_TOK + c * CS + j) * FM + g * 16;
    uint4 k0 = *reinterpret_cast<const uint4*>(ks);
    uint4 k1 = *reinterpret_cast<const uint4*>(ks + 8);
    pv = (const unsigned short*)&k0;
    #pragma unroll
    for (int e = 0; e < 8; e++) sPkt[(g * 16 + e) * LD + j] = (short)pv[e];
    pv = (const unsigned short*)&k1;
    #pragma unroll
    for (int e = 0; e < 8; e++) sPkt[(g * 16 + 8 + e) * LD + j] = (short)pv[e];
  }
  __syncthreads();

  const int frow = lane & 15, fk = (lane >> 4) * 8;
  const int rowW = wv * 16;

  f32x4 acc[4];
  #pragma unroll
  for (int mt = 0; mt < 4; mt++) acc[mt] = (f32x4){0.f, 0.f, 0.f, 0.f};
  #pragma unroll
  for (int ks = 0; ks < 64; ks += 32) {
    bf16x8 a = *reinterpret_cast<const bf16x8*>(&sVt[(rowW + frow) * LD + ks + fk]);
    #pragma unroll
    for (int mt = 0; mt < 4; mt++) {
      bf16x8 b = *reinterpret_cast<const bf16x8*>(&sPkt[(mt * 16 + frow) * LD + ks + fk]);
      acc[mt] = __builtin_amdgcn_mfma_f32_16x16x32_bf16(a, b, acc[mt], 0, 0, 0);
    }
  }

  {
    int m = tid >> 2, q = tid & 3;
    float s = 0.f;
    #pragma unroll
    for (int e = 0; e < 16; e++)
      s += b2f(*reinterpret_cast<bf16*>(&sPkt[m * LD + q * 16 + e]));
    sCp[m][q] = s;
  }
  __syncthreads();
  if (tid < 64)
    ck[((size_t)h * NC + c) * FM + tid] = sCp[tid][0] + sCp[tid][1] + sCp[tid][2] + sCp[tid][3];

  float* dst = ckv_t + ((size_t)h * NC + c) * 4096;
  #pragma unroll
  for (int mt = 0; mt < 4; mt++)
    #pragma unroll
    for (int reg = 0; reg < 4; reg++) {
      int gd = rowW + (lane >> 4) * 4 + reg;
      int gm = mt * 16 + (lane & 15);
      dst[gd * 64 + gm] = acc[mt][reg];
    }
}

// Register-blocked exclusive prefix over chunks (layout-agnostic).
__global__ __launch_bounds__(256) void prefix_chunks(
    float* __restrict__ ckv, float* __restrict__ ck)
{
  const int h = blockIdx.x, g = blockIdx.y;
  const int cell = g * 256 + threadIdx.x;
  const size_t base = (size_t)h * NC * 4096 + cell;
  float v[NC];
  #pragma unroll
  for (int c = 0; c < NC; c++) v[c] = ckv[base + (size_t)c * 4096];
  float run = 0.f;
  #pragma unroll
  for (int c = 0; c < NC; c++) { float t = v[c]; ckv[base + (size_t)c * 4096] = run; run += t; }
  if (g == 0 && threadIdx.x < 64) {
    const size_t b2 = (size_t)h * NC * FM + threadIdx.x;
    float u[NC];
    #pragma unroll
    for (int c = 0; c < NC; c++) u[c] = ck[b2 + (size_t)c * FM];
    float r2 = 0.f;
    #pragma unroll
    for (int c = 0; c < NC; c++) { float t = u[c]; ck[b2 + (size_t)c * FM] = r2; r2 += t; }
  }
}

// MFMA causal chunk attention.
__global__ __launch_bounds__(256) void attn_chunk(
    const bf16* __restrict__ phiq, const bf16* __restrict__ phik,
    const bf16* __restrict__ vf, const float* __restrict__ ckv_t,
    const float* __restrict__ ck, bf16* __restrict__ attn_out)
{
  constexpr int LD = 72;
  __shared__ short sPq[64 * LD];
  __shared__ short sPk[64 * LD];
  __shared__ short sAl[64 * LD];
  __shared__ short sVt[64 * LD];
  __shared__ short sSh[64 * LD];
  __shared__ short sSl[64 * LD];
  __shared__ float sKc[64];
  __shared__ float sDp[64][4];
  __shared__ float sDen[64];

  const int c = blockIdx.x, h = blockIdx.y;
  const int tid = threadIdx.x, lane = tid & 63, wv = tid >> 6;

  {
    int r = tid >> 2, g = tid & 3;
    const size_t gb = ((size_t)h * N_TOK + c * CS + r) * FM + g * 16;
    uint4 q0 = *reinterpret_cast<const uint4*>(phiq + gb);
    uint4 q1 = *reinterpret_cast<const uint4*>(phiq + gb + 8);
    uint4 k0 = *reinterpret_cast<const uint4*>(phik + gb);
    uint4 k1 = *reinterpret_cast<const uint4*>(phik + gb + 8);
    int o = r * LD + g * 16;
    *reinterpret_cast<uint4*>(&sPq[o]) = q0; *reinterpret_cast<uint4*>(&sPq[o + 8]) = q1;
    *reinterpret_cast<uint4*>(&sPk[o]) = k0; *reinterpret_cast<uint4*>(&sPk[o + 8]) = k1;
  }
  {
    int j = tid >> 2, g = tid & 3;
    const bf16* vs = vf + (size_t)(c * CS + j) * DIMM + h * HD + g * 16;
    uint4 v0 = *reinterpret_cast<const uint4*>(vs);
    uint4 v1 = *reinterpret_cast<const uint4*>(vs + 8);
    const unsigned short* pv = (const unsigned short*)&v0;
    #pragma unroll
    for (int e = 0; e < 8; e++) sVt[(g * 16 + e) * LD + j] = (short)pv[e];
    pv = (const unsigned short*)&v1;
    #pragma unroll
    for (int e = 0; e < 8; e++) sVt[(g * 16 + 8 + e) * LD + j] = (short)pv[e];
  }
  {
    int d = tid >> 2, mg = tid & 3;
    const float* src = ckv_t + ((size_t)h * NC + c) * 4096 + d * 64 + mg * 16;
    int o = d * LD + mg * 16;
    #pragma unroll
    for (int e4 = 0; e4 < 4; e4++) {
      float4 v = *reinterpret_cast<const float4*>(src + e4 * 4);
      uint2 ph, pl;
      split_pack_bf(v, ph, pl);
      *reinterpret_cast<uint2*>(&sSh[o + e4 * 4]) = ph;
      *reinterpret_cast<uint2*>(&sSl[o + e4 * 4]) = pl;
    }
  }
  if (tid < 64) sKc[tid] = ck[((size_t)h * NC + c) * FM + tid];
  __syncthreads();

  const int frow = lane & 15, fk = (lane >> 4) * 8;
  const int rowW = wv * 16;

  f32x4 accA[4];
  #pragma unroll
  for (int ct = 0; ct < 4; ct++) accA[ct] = (f32x4){0.f, 0.f, 0.f, 0.f};
  #pragma unroll
  for (int ks = 0; ks < 64; ks += 32) {
    bf16x8 a = *reinterpret_cast<const bf16x8*>(&sPq[(rowW + frow) * LD + ks + fk]);
    #pragma unroll
    for (int ct = 0; ct < 4; ct++) {
      bf16x8 b = *reinterpret_cast<const bf16x8*>(&sPk[(ct * 16 + frow) * LD + ks + fk]);
      accA[ct] = __builtin_amdgcn_mfma_f32_16x16x32_bf16(a, b, accA[ct], 0, 0, 0);
    }
  }
  __syncthreads();

  #pragma unroll
  for (int ct = 0; ct < 4; ct++)
    #pragma unroll
    for (int reg = 0; reg < 4; reg++) {
      int gi = rowW + (lane >> 4) * 4 + reg;
      int gj = ct * 16 + (lane & 15);
      float av = (gj <= gi) ? accA[ct][reg] : 0.f;
      bf16 hb = __float2bfloat16(av);
      sPk[gi * LD + gj] = *reinterpret_cast<short*>(&hb);
      unsigned short lu = f2bfu(av - b2f(hb));
      sAl[gi * LD + gj] = (short)lu;
    }
  __syncthreads();

  {
    int i = tid >> 2, q = tid & 3;
    float p = 0.f;
    #pragma unroll
    for (int e = 0; e < 16; e++) {
      int m = q * 16 + e;
      p += b2f(*reinterpret_cast<bf16*>(&sPq[i * LD + m])) * sKc[m];
      p += b2f(*reinterpret_cast<bf16*>(&sPk[i * LD + m]))
         + b2f(*reinterpret_cast<bf16*>(&sAl[i * LD + m]));
    }
    sDp[i][q] = p;
  }

  f32x4 accO[4];
  #pragma unroll
  for (int dt = 0; dt < 4; dt++) accO[dt] = (f32x4){0.f, 0.f, 0.f, 0.f};
  #pragma unroll
  for (int ks = 0; ks < 64; ks += 32) {
    bf16x8 ah = *reinterpret_cast<const bf16x8*>(&sPk[(rowW + frow) * LD + ks + fk]);
    bf16x8 al = *reinterpret_cast<const bf16x8*>(&sAl[(rowW + frow) * LD + ks + fk]);
    bf16x8 aq = *reinterpret_cast<const bf16x8*>(&sPq[(rowW + frow) * LD + ks + fk]);
    #pragma unroll
    for (int dt = 0; dt < 4; dt++) {
      bf16x8 bv = *reinterpret_cast<const bf16x8*>(&sVt[(dt * 16 + frow) * LD + ks + fk]);
      bf16x8 bh = *reinterpret_cast<const bf16x8*>(&sSh[(dt * 16 + frow) * LD + ks + fk]);
      bf16x8 bl = *reinterpret_cast<const bf16x8*>(&sSl[(dt * 16 + frow) * LD + ks + fk]);
      accO[dt] = __builtin_amdgcn_mfma_f32_16x16x32_bf16(ah, bv, accO[dt], 0, 0, 0);
      accO[dt] = __builtin_amdgcn_mfma_f32_16x16x32_bf16(al, bv, accO[dt], 0, 0, 0);
      accO[dt] = __builtin_amdgcn_mfma_f32_16x16x32_bf16(aq, bh, accO[dt], 0, 0, 0);
      accO[dt] = __builtin_amdgcn_mfma_f32_16x16x32_bf16(aq, bl, accO[dt], 0, 0, 0);
    }
  }
  __syncthreads();
  if (tid < 64) {
    float den = sDp[tid][0] + sDp[tid][1] + sDp[tid][2] + sDp[tid][3];
    sDen[tid] = 1.f / (den + 1e-6f);
  }
  __syncthreads();

  #pragma unroll
  for (int dt = 0; dt < 4; dt++)
    #pragma unroll
    for (int reg = 0; reg < 4; reg++) {
      int gi = rowW + (lane >> 4) * 4 + reg;
      int gd = dt * 16 + (lane & 15);
      float v = accO[dt][reg] * sDen[gi];
      attn_out[(size_t)(c * CS + gi) * DIMM + h * HD + gd] = __float2bfloat16(v);
    }
}

extern "C" void kernel_launch(void* const* d_in, const int* in_sizes, int n_in,
                              void* d_out, int out_size, void* d_ws, size_t ws_size,
                              hipStream_t stream) {
  (void)in_sizes; (void)n_in; (void)out_size; (void)ws_size;
  const float* x     = (const float*)d_in[0];
  const float* omega = (const float*)d_in[1];
  const float* wq    = (const float*)d_in[2];
  const float* wk    = (const float*)d_in[3];
  const float* wv    = (const float*)d_in[4];
  const float* wo    = (const float*)d_in[5];
  const float* bo    = (const float*)d_in[6];
  float* out = (float*)d_out;

  char* w = (char*)d_ws;
  _Float16* x16   = (_Float16*)(w);                  // 4 MB  [later: attn bf16 alias]
  _Float16* w16   = (_Float16*)(w + (4u  << 20));    // 6 MB
  bf16*     wo_bf = (bf16*)   (w + (10u << 20));     // 2 MB
  bf16*     vbf   = (bf16*)   (w + (12u << 20));     // 4 MB
  bf16*     phiq  = (bf16*)   (w + (16u << 20));     // 4 MB
  bf16*     phik  = (bf16*)   (w + (20u << 20));     // 4 MB
  float*    ckv   = (float*)  (w + (24u << 20));     // 8 MB (transposed [d][m])
  float*    ck    = (float*)  (w + (32u << 20));     // 128 KB
  bf16*     attnb = (bf16*)x16;

  cvt_all<<<6144, 256, 0, stream>>>((const float4*)x, (const float4*)wq,
                                    (const float4*)wk, (const float4*)wv,
                                    (const float4*)wo,
                                    x16, w16, wo_bf);

  gemm_qkv_phi<<<dim3(24, 16), 512, 0, stream>>>(x16, w16, omega, phiq, phik, vbf);

  chunk_sum<<<dim3(NC, NH), 256, 0, stream>>>(phik, vbf, ckv, ck);
  prefix_chunks<<<dim3(NH, 16), 256, 0, stream>>>(ckv, ck);
  attn_chunk<<<dim3(NC, NH), 256, 0, stream>>>(phiq, phik, vbf, ckv, ck, attnb);

  gemm_bf16_out<<<dim3(8, 32), 512, 0, stream>>>(attnb, wo_bf, bo, out);
}

// Round 7
// 140.590 us; speedup vs baseline: 1.2594x; 1.2594x over previous
//
#include <hip/hip_runtime.h>
#include <hip/hip_bf16.h>

typedef __hip_bfloat16 bf16;
typedef __attribute__((ext_vector_type(8))) short bf16x8;
typedef __attribute__((ext_vector_type(8))) _Float16 f16x8;
typedef __attribute__((ext_vector_type(4))) float f32x4;

constexpr int N_TOK = 2048;
constexpr int DIMM  = 1024;
constexpr int NH    = 16;
constexpr int HD    = 64;
constexpr int FM    = 64;
constexpr int NC    = 32;
constexpr int CS    = 64;

__device__ __forceinline__ float b2f(bf16 v) { return __bfloat162float(v); }
__device__ __forceinline__ unsigned short f2bfu(float v) {
  bf16 h = __float2bfloat16(v);
  return *reinterpret_cast<unsigned short*>(&h);
}
__device__ __forceinline__ unsigned short f2hu(float v) {
  _Float16 h = (_Float16)v;
  return *reinterpret_cast<unsigned short*>(&h);
}

__device__ __forceinline__ void gl_lds16(const void* g, short* l) {
  __builtin_amdgcn_global_load_lds(
      (const __attribute__((address_space(1))) void*)g,
      (__attribute__((address_space(3))) void*)l, 16, 0, 0);
}

// Fused conversions: x -> fp16; wq|wk|wv -> fp16 [3072][1024]; wo -> bf16.
__global__ __launch_bounds__(256) void cvt_all(
    const float4* __restrict__ x, const float4* __restrict__ wq,
    const float4* __restrict__ wk, const float4* __restrict__ wv,
    const float4* __restrict__ wo,
    _Float16* __restrict__ x16, _Float16* __restrict__ w16,
    bf16* __restrict__ wo_bf)
{
  int i = blockIdx.x * 256 + threadIdx.x;   // < 1572864
  if (i < 524288) {
    float4 v = x[i];
    uint2 p = { (unsigned)f2hu(v.x) | ((unsigned)f2hu(v.y) << 16),
                (unsigned)f2hu(v.z) | ((unsigned)f2hu(v.w) << 16) };
    reinterpret_cast<uint2*>(x16)[i] = p;
  } else if (i < 1310720) {
    int j = i - 524288;
    const float4* src = (j < 262144) ? wq : (j < 524288) ? wk : wv;
    int jj = (j < 262144) ? j : (j < 524288) ? j - 262144 : j - 524288;
    float4 v = src[jj];
    uint2 p = { (unsigned)f2hu(v.x) | ((unsigned)f2hu(v.y) << 16),
                (unsigned)f2hu(v.z) | ((unsigned)f2hu(v.w) << 16) };
    reinterpret_cast<uint2*>(w16)[j] = p;
  } else {
    int j = i - 1310720;
    float4 v = wo[j];
    uint2 p = { (unsigned)f2bfu(v.x) | ((unsigned)f2bfu(v.y) << 16),
                (unsigned)f2bfu(v.z) | ((unsigned)f2bfu(v.w) << 16) };
    reinterpret_cast<uint2*>(wo_bf)[j] = p;
  }
}

// Fused QKV projection + phi feature map (ROUND-0 VERSION — measured best).
// Main GEMM: single fp16 MFMA, 128x128 tile, BK=32, dbuf 32 KB, 8 waves (64x32/wave).
__global__ __launch_bounds__(512, 4) void gemm_qkv_phi(
    const _Float16* __restrict__ A16, const _Float16* __restrict__ B16,
    const float* __restrict__ omega,
    bf16* __restrict__ phiq, bf16* __restrict__ phik, bf16* __restrict__ Cv)
{
  constexpr int K = 1024;
  __shared__ alignas(16) char smemRaw[32768];
  short* sA = (short*)smemRaw;       // [2][4096] main loop
  short* sB = sA + 8192;             // [2][4096]

  const int tid = threadIdx.x, lane = tid & 63, wv = tid >> 6;   // wv 0..7
  const int colBase = blockIdx.x * 128, rowBase = blockIdx.y * 128;
  const int waveRow = (wv >> 2) * 64, waveCol = (wv & 3) * 32;
  const int stR = tid >> 2, stK = (tid & 3) * 8;

  const _Float16* gA = A16 + (size_t)(rowBase + stR) * K + stK;
  const _Float16* gB = B16 + (size_t)(colBase + stR) * K + stK;
  const int ldsOff = wv * 512;

  f32x4 acc[4][2];
  #pragma unroll
  for (int r = 0; r < 4; r++)
    #pragma unroll
    for (int c = 0; c < 2; c++) acc[r][c] = (f32x4){0.f, 0.f, 0.f, 0.f};

  const int frow = lane & 15, fk = (lane >> 4) * 8, quad = lane >> 4;
  const int nIter = K / 32;

  gl_lds16(gA, &sA[ldsOff]);
  gl_lds16(gB, &sB[ldsOff]);

  int buf = 0;
  for (int it = 0; it < nIter; it++) {
    __syncthreads();
    if (it + 1 < nIter) {
      const size_t kb = (size_t)(it + 1) * 32;
      const int nb = buf ^ 1;
      gl_lds16(gA + kb, &sA[nb * 4096 + ldsOff]);
      gl_lds16(gB + kb, &sB[nb * 4096 + ldsOff]);
    }
    f16x8 a[4], b[2];
    #pragma unroll
    for (int r = 0; r < 4; r++)
      a[r] = *reinterpret_cast<const f16x8*>(&sA[buf * 4096 + (waveRow + r * 16 + frow) * 32 + fk]);
    #pragma unroll
    for (int c = 0; c < 2; c++)
      b[c] = *reinterpret_cast<const f16x8*>(&sB[buf * 4096 + (waveCol + c * 16 + frow) * 32 + fk]);
    #pragma unroll
    for (int r = 0; r < 4; r++)
      #pragma unroll
      for (int c = 0; c < 2; c++)
        acc[r][c] = __builtin_amdgcn_mfma_f32_16x16x32_f16(a[r], b[c], acc[r][c], 0, 0, 0);
    buf ^= 1;
  }
  __syncthreads();   // all main-loop LDS reads done before union reuse / exit

  if (colBase >= 2048) {
    #pragma unroll
    for (int r = 0; r < 4; r++)
      #pragma unroll
      for (int c = 0; c < 2; c++)
        #pragma unroll
        for (int reg = 0; reg < 4; reg++) {
          int row = rowBase + waveRow + r * 16 + quad * 4 + reg;
          int col = colBase - 2048 + waveCol + c * 16 + (lane & 15);
          Cv[(size_t)row * 1024 + col] = __float2bfloat16(acc[r][c][reg]);
        }
    return;
  }

  // --- phi phase (q or k) --- LDS: sQ16 18432 + sO16 9216 + sNorm 1024 = 28672 B
  constexpr int LD = 72;
  short* sQ16 = (short*)smemRaw;          // [128][72] fp16, one head at a time
  short* sO16 = sQ16 + 9216;              // [64][72] fp16
  float* sNorm = (float*)(sO16 + 4608);   // [2][128]

  const bool isQ = (colBase < 1024);
  const int hPairBase = (isQ ? colBase : (colBase - 1024)) >> 6;
  bf16* dstBase = isQ ? phiq : phik;
  const int headSel = (wv & 3) >> 1;

  // stage omega fp16 (8 floats/thread -> one 16B write); zero norms
  {
    int r = tid >> 3, cg2 = (tid & 7) * 8;
    const float* src = omega + r * 64 + cg2;
    float4 v0 = *reinterpret_cast<const float4*>(src);
    float4 v1 = *reinterpret_cast<const float4*>(src + 4);
    uint4 p = { (unsigned)f2hu(v0.x) | ((unsigned)f2hu(v0.y) << 16),
                (unsigned)f2hu(v0.z) | ((unsigned)f2hu(v0.w) << 16),
                (unsigned)f2hu(v1.x) | ((unsigned)f2hu(v1.y) << 16),
                (unsigned)f2hu(v1.z) | ((unsigned)f2hu(v1.w) << 16) };
    *reinterpret_cast<uint4*>(&sO16[r * LD + cg2]) = p;
  }
  if (tid < 256) sNorm[tid] = 0.f;
  __syncthreads();

  // per-row ||q||^2 partials: in-quad shuffle reduce, LDS atomic (exact fp32)
  #pragma unroll
  for (int r = 0; r < 4; r++)
    #pragma unroll
    for (int reg = 0; reg < 4; reg++) {
      float s = acc[r][0][reg] * acc[r][0][reg] + acc[r][1][reg] * acc[r][1][reg];
      s += __shfl_xor(s, 1); s += __shfl_xor(s, 2);
      s += __shfl_xor(s, 4); s += __shfl_xor(s, 8);
      if ((lane & 15) == 0) {
        int row = waveRow + r * 16 + quad * 4 + reg;
        atomicAdd(&sNorm[headSel * 128 + row], s);
      }
    }

  #pragma unroll
  for (int hh = 0; hh < 2; hh++) {
    if (headSel == hh) {
      // stage this head's q tile as fp16 from fp32 accs
      #pragma unroll
      for (int r = 0; r < 4; r++)
        #pragma unroll
        for (int c = 0; c < 2; c++)
          #pragma unroll
          for (int reg = 0; reg < 4; reg++) {
            int row = waveRow + r * 16 + quad * 4 + reg;
            int lc = (waveCol & 63) + c * 16 + (lane & 15);
            sQ16[row * LD + lc] = (short)f2hu(acc[r][c][reg]);
          }
    }
    __syncthreads();

    // proj = q . omega^T, single fp16 MFMA product; wave wv does rows wv*16..+15
    f32x4 acc2[4];
    #pragma unroll
    for (int ct = 0; ct < 4; ct++) acc2[ct] = (f32x4){0.f, 0.f, 0.f, 0.f};
    #pragma unroll
    for (int ks = 0; ks < 64; ks += 32) {
      f16x8 a = *reinterpret_cast<const f16x8*>(&sQ16[(wv * 16 + frow) * LD + ks + fk]);
      #pragma unroll
      for (int ct = 0; ct < 4; ct++) {
        f16x8 b = *reinterpret_cast<const f16x8*>(&sO16[(ct * 16 + frow) * LD + ks + fk]);
        acc2[ct] = __builtin_amdgcn_mfma_f32_16x16x32_f16(a, b, acc2[ct], 0, 0, 0);
      }
    }
    // phi epilogue
    const int h = hPairBase + hh;
    #pragma unroll
    for (int ct = 0; ct < 4; ct++)
      #pragma unroll
      for (int reg = 0; reg < 4; reg++) {
        int row = wv * 16 + quad * 4 + reg;
        int m = ct * 16 + (lane & 15);
        float norm = 0.5f * sNorm[hh * 128 + row];
        float v = __expf(fminf(acc2[ct][reg] - norm, 80.f)) * 0.125f;
        dstBase[((size_t)h * N_TOK + rowBase + row) * FM + m] = __float2bfloat16(v);
      }
    __syncthreads();   // before next head overwrites sQ16
  }
}

// Output projection: bf16 NT GEMM + bias, fp32 out. Block 64x128, 512 threads
// = 8 waves (2x4, wave tile 32x32), dbuf LDS 24 KB. Grid (8,32)=256 blocks.
__global__ __launch_bounds__(512) void gemm_bf16_out(
    const bf16* __restrict__ A, const bf16* __restrict__ B,
    const float* __restrict__ bias, float* __restrict__ C)
{
  constexpr int K = 1024;
  __shared__ short sA[2][2048], sB[2][4096];
  const int tid = threadIdx.x, lane = tid & 63, wv = tid >> 6;
  const int rowBase = blockIdx.y * 64, colBase = blockIdx.x * 128;
  const int waveRow = (wv >> 2) * 32, waveCol = (wv & 3) * 32;
  const int stR = tid >> 2, stK = (tid & 3) * 8;
  const bf16* gA = A + (size_t)(rowBase + stR) * K + stK;   // valid for wv<4 only
  const bf16* gB = B + (size_t)(colBase + stR) * K + stK;
  const int ldsOff = wv * 512;

  f32x4 acc[2][2];
  #pragma unroll
  for (int r = 0; r < 2; r++)
    #pragma unroll
    for (int c = 0; c < 2; c++) acc[r][c] = (f32x4){0.f, 0.f, 0.f, 0.f};

  const int frow = lane & 15, fk = (lane >> 4) * 8;
  const int nIter = K / 32;

  if (wv < 4) gl_lds16(gA, &sA[0][ldsOff]);
  gl_lds16(gB, &sB[0][ldsOff]);

  int buf = 0;
  for (int it = 0; it < nIter; it++) {
    __syncthreads();
    if (it + 1 < nIter) {
      const size_t kb = (size_t)(it + 1) * 32;
      const int nb = buf ^ 1;
      if (wv < 4) gl_lds16(gA + kb, &sA[nb][ldsOff]);
      gl_lds16(gB + kb, &sB[nb][ldsOff]);
    }
    bf16x8 a[2], b[2];
    #pragma unroll
    for (int r = 0; r < 2; r++)
      a[r] = *reinterpret_cast<const bf16x8*>(&sA[buf][(waveRow + r * 16 + frow) * 32 + fk]);
    #pragma unroll
    for (int c = 0; c < 2; c++)
      b[c] = *reinterpret_cast<const bf16x8*>(&sB[buf][(waveCol + c * 16 + frow) * 32 + fk]);
    #pragma unroll
    for (int r = 0; r < 2; r++)
      #pragma unroll
      for (int c = 0; c < 2; c++)
        acc[r][c] = __builtin_amdgcn_mfma_f32_16x16x32_bf16(a[r], b[c], acc[r][c], 0, 0, 0);
    buf ^= 1;
  }

  #pragma unroll
  for (int r = 0; r < 2; r++)
    #pragma unroll
    for (int c = 0; c < 2; c++)
      #pragma unroll
      for (int reg = 0; reg < 4; reg++) {
        int row = rowBase + waveRow + r * 16 + (lane >> 4) * 4 + reg;
        int col = colBase + waveCol + c * 16 + (lane & 15);
        C[(size_t)row * 1024 + col] = acc[r][c][reg] + bias[col];
      }
}

// MFMA chunk sums: ckv_t[h][c][d][m] = sum_j v[j][d]*phik[j][m]; ck = col sums of phik.
__global__ __launch_bounds__(256) void chunk_sum(
    const bf16* __restrict__ phik, const bf16* __restrict__ vf,
    float* __restrict__ ckv_t, float* __restrict__ ck)
{
  constexpr int LD = 72;
  __shared__ short sVt[64 * LD], sPkt[64 * LD];
  __shared__ float sCp[64][4];
  const int c = blockIdx.x, h = blockIdx.y;
  const int tid = threadIdx.x, lane = tid & 63, wv = tid >> 6;

  {
    int j = tid >> 2, g = tid & 3;
    const bf16* vs = vf + (size_t)(c * CS + j) * DIMM + h * HD + g * 16;
    uint4 v0 = *reinterpret_cast<const uint4*>(vs);
    uint4 v1 = *reinterpret_cast<const uint4*>(vs + 8);
    const unsigned short* pv = (const unsigned short*)&v0;
    #pragma unroll
    for (int e = 0; e < 8; e++) sVt[(g * 16 + e) * LD + j] = (short)pv[e];
    pv = (const unsigned short*)&v1;
    #pragma unroll
    for (int e = 0; e < 8; e++) sVt[(g * 16 + 8 + e) * LD + j] = (short)pv[e];

    const bf16* ks = phik + ((size_t)h * N_TOK + c * CS + j) * FM + g * 16;
    uint4 k0 = *reinterpret_cast<const uint4*>(ks);
    uint4 k1 = *reinterpret_cast<const uint4*>(ks + 8);
    pv = (const unsigned short*)&k0;
    #pragma unroll
    for (int e = 0; e < 8; e++) sPkt[(g * 16 + e) * LD + j] = (short)pv[e];
    pv = (const unsigned short*)&k1;
    #pragma unroll
    for (int e = 0; e < 8; e++) sPkt[(g * 16 + 8 + e) * LD + j] = (short)pv[e];
  }
  __syncthreads();

  const int frow = lane & 15, fk = (lane >> 4) * 8;
  const int rowW = wv * 16;

  f32x4 acc[4];
  #pragma unroll
  for (int mt = 0; mt < 4; mt++) acc[mt] = (f32x4){0.f, 0.f, 0.f, 0.f};
  #pragma unroll
  for (int ks = 0; ks < 64; ks += 32) {
    bf16x8 a = *reinterpret_cast<const bf16x8*>(&sVt[(rowW + frow) * LD + ks + fk]);
    #pragma unroll
    for (int mt = 0; mt < 4; mt++) {
      bf16x8 b = *reinterpret_cast<const bf16x8*>(&sPkt[(mt * 16 + frow) * LD + ks + fk]);
      acc[mt] = __builtin_amdgcn_mfma_f32_16x16x32_bf16(a, b, acc[mt], 0, 0, 0);
    }
  }

  {
    int m = tid >> 2, q = tid & 3;
    float s = 0.f;
    #pragma unroll
    for (int e = 0; e < 16; e++)
      s += b2f(*reinterpret_cast<bf16*>(&sPkt[m * LD + q * 16 + e]));
    sCp[m][q] = s;
  }
  __syncthreads();
  if (tid < 64)
    ck[((size_t)h * NC + c) * FM + tid] = sCp[tid][0] + sCp[tid][1] + sCp[tid][2] + sCp[tid][3];

  float* dst = ckv_t + ((size_t)h * NC + c) * 4096;
  #pragma unroll
  for (int mt = 0; mt < 4; mt++)
    #pragma unroll
    for (int reg = 0; reg < 4; reg++) {
      int gd = rowW + (lane >> 4) * 4 + reg;
      int gm = mt * 16 + (lane & 15);
      dst[gd * 64 + gm] = acc[mt][reg];
    }
}

// Register-blocked exclusive prefix over chunks. NEW: emits the exclusive
// state directly as bf16 hi/lo pairs (the exact split attn_chunk used to
// compute per-block), so attn staging becomes plain uint4 copies.
__global__ __launch_bounds__(256) void prefix_chunks(
    const float* __restrict__ ckv, float* __restrict__ ck,
    bf16* __restrict__ ckv_h, bf16* __restrict__ ckv_l)
{
  const int h = blockIdx.x, g = blockIdx.y;
  const int cell = g * 256 + threadIdx.x;
  const size_t base = (size_t)h * NC * 4096 + cell;
  float v[NC];
  #pragma unroll
  for (int c = 0; c < NC; c++) v[c] = ckv[base + (size_t)c * 4096];
  float run = 0.f;
  #pragma unroll
  for (int c = 0; c < NC; c++) {
    bf16 hb = __float2bfloat16(run);
    ckv_h[base + (size_t)c * 4096] = hb;
    ckv_l[base + (size_t)c * 4096] = __float2bfloat16(run - b2f(hb));
    run += v[c];
  }
  if (g == 0 && threadIdx.x < 64) {
    const size_t b2 = (size_t)h * NC * FM + threadIdx.x;
    float u[NC];
    #pragma unroll
    for (int c = 0; c < NC; c++) u[c] = ck[b2 + (size_t)c * FM];
    float r2 = 0.f;
    #pragma unroll
    for (int c = 0; c < NC; c++) { float t = u[c]; ck[b2 + (size_t)c * FM] = r2; r2 += t; }
  }
}

// MFMA causal chunk attention. State arrives pre-split as bf16 hi/lo.
__global__ __launch_bounds__(256) void attn_chunk(
    const bf16* __restrict__ phiq, const bf16* __restrict__ phik,
    const bf16* __restrict__ vf, const bf16* __restrict__ ckv_h,
    const bf16* __restrict__ ckv_l,
    const float* __restrict__ ck, bf16* __restrict__ attn_out)
{
  constexpr int LD = 72;
  __shared__ short sPq[64 * LD];
  __shared__ short sPk[64 * LD];
  __shared__ short sAl[64 * LD];
  __shared__ short sVt[64 * LD];
  __shared__ short sSh[64 * LD];
  __shared__ short sSl[64 * LD];
  __shared__ float sKc[64];
  __shared__ float sDp[64][4];
  __shared__ float sDen[64];

  const int c = blockIdx.x, h = blockIdx.y;
  const int tid = threadIdx.x, lane = tid & 63, wv = tid >> 6;

  {
    int r = tid >> 2, g = tid & 3;
    const size_t gb = ((size_t)h * N_TOK + c * CS + r) * FM + g * 16;
    uint4 q0 = *reinterpret_cast<const uint4*>(phiq + gb);
    uint4 q1 = *reinterpret_cast<const uint4*>(phiq + gb + 8);
    uint4 k0 = *reinterpret_cast<const uint4*>(phik + gb);
    uint4 k1 = *reinterpret_cast<const uint4*>(phik + gb + 8);
    int o = r * LD + g * 16;
    *reinterpret_cast<uint4*>(&sPq[o]) = q0; *reinterpret_cast<uint4*>(&sPq[o + 8]) = q1;
    *reinterpret_cast<uint4*>(&sPk[o]) = k0; *reinterpret_cast<uint4*>(&sPk[o + 8]) = k1;
  }
  {
    int j = tid >> 2, g = tid & 3;
    const bf16* vs = vf + (size_t)(c * CS + j) * DIMM + h * HD + g * 16;
    uint4 v0 = *reinterpret_cast<const uint4*>(vs);
    uint4 v1 = *reinterpret_cast<const uint4*>(vs + 8);
    const unsigned short* pv = (const unsigned short*)&v0;
    #pragma unroll
    for (int e = 0; e < 8; e++) sVt[(g * 16 + e) * LD + j] = (short)pv[e];
    pv = (const unsigned short*)&v1;
    #pragma unroll
    for (int e = 0; e < 8; e++) sVt[(g * 16 + 8 + e) * LD + j] = (short)pv[e];
  }
  {
    int d = tid >> 2, mg = tid & 3;
    const size_t sb = ((size_t)h * NC + c) * 4096 + d * 64 + mg * 16;
    int o = d * LD + mg * 16;
    *reinterpret_cast<uint4*>(&sSh[o])     = *reinterpret_cast<const uint4*>(ckv_h + sb);
    *reinterpret_cast<uint4*>(&sSh[o + 8]) = *reinterpret_cast<const uint4*>(ckv_h + sb + 8);
    *reinterpret_cast<uint4*>(&sSl[o])     = *reinterpret_cast<const uint4*>(ckv_l + sb);
    *reinterpret_cast<uint4*>(&sSl[o + 8]) = *reinterpret_cast<const uint4*>(ckv_l + sb + 8);
  }
  if (tid < 64) sKc[tid] = ck[((size_t)h * NC + c) * FM + tid];
  __syncthreads();

  const int frow = lane & 15, fk = (lane >> 4) * 8;
  const int rowW = wv * 16;

  f32x4 accA[4];
  #pragma unroll
  for (int ct = 0; ct < 4; ct++) accA[ct] = (f32x4){0.f, 0.f, 0.f, 0.f};
  #pragma unroll
  for (int ks = 0; ks < 64; ks += 32) {
    bf16x8 a = *reinterpret_cast<const bf16x8*>(&sPq[(rowW + frow) * LD + ks + fk]);
    #pragma unroll
    for (int ct = 0; ct < 4; ct++) {
      bf16x8 b = *reinterpret_cast<const bf16x8*>(&sPk[(ct * 16 + frow) * LD + ks + fk]);
      accA[ct] = __builtin_amdgcn_mfma_f32_16x16x32_bf16(a, b, accA[ct], 0, 0, 0);
    }
  }
  __syncthreads();

  #pragma unroll
  for (int ct = 0; ct < 4; ct++)
    #pragma unroll
    for (int reg = 0; reg < 4; reg++) {
      int gi = rowW + (lane >> 4) * 4 + reg;
      int gj = ct * 16 + (lane & 15);
      float av = (gj <= gi) ? accA[ct][reg] : 0.f;
      bf16 hb = __float2bfloat16(av);
      sPk[gi * LD + gj] = *reinterpret_cast<short*>(&hb);
      unsigned short lu = f2bfu(av - b2f(hb));
      sAl[gi * LD + gj] = (short)lu;
    }
  __syncthreads();

  {
    int i = tid >> 2, q = tid & 3;
    float p = 0.f;
    #pragma unroll
    for (int e = 0; e < 16; e++) {
      int m = q * 16 + e;
      p += b2f(*reinterpret_cast<bf16*>(&sPq[i * LD + m])) * sKc[m];
      p += b2f(*reinterpret_cast<bf16*>(&sPk[i * LD + m]))
         + b2f(*reinterpret_cast<bf16*>(&sAl[i * LD + m]));
    }
    sDp[i][q] = p;
  }

  f32x4 accO[4];
  #pragma unroll
  for (int dt = 0; dt < 4; dt++) accO[dt] = (f32x4){0.f, 0.f, 0.f, 0.f};
  #pragma unroll
  for (int ks = 0; ks < 64; ks += 32) {
    bf16x8 ah = *reinterpret_cast<const bf16x8*>(&sPk[(rowW + frow) * LD + ks + fk]);
    bf16x8 al = *reinterpret_cast<const bf16x8*>(&sAl[(rowW + frow) * LD + ks + fk]);
    bf16x8 aq = *reinterpret_cast<const bf16x8*>(&sPq[(rowW + frow) * LD + ks + fk]);
    #pragma unroll
    for (int dt = 0; dt < 4; dt++) {
      bf16x8 bv = *reinterpret_cast<const bf16x8*>(&sVt[(dt * 16 + frow) * LD + ks + fk]);
      bf16x8 bh = *reinterpret_cast<const bf16x8*>(&sSh[(dt * 16 + frow) * LD + ks + fk]);
      bf16x8 bl = *reinterpret_cast<const bf16x8*>(&sSl[(dt * 16 + frow) * LD + ks + fk]);
      accO[dt] = __builtin_amdgcn_mfma_f32_16x16x32_bf16(ah, bv, accO[dt], 0, 0, 0);
      accO[dt] = __builtin_amdgcn_mfma_f32_16x16x32_bf16(al, bv, accO[dt], 0, 0, 0);
      accO[dt] = __builtin_amdgcn_mfma_f32_16x16x32_bf16(aq, bh, accO[dt], 0, 0, 0);
      accO[dt] = __builtin_amdgcn_mfma_f32_16x16x32_bf16(aq, bl, accO[dt], 0, 0, 0);
    }
  }
  __syncthreads();
  if (tid < 64) {
    float den = sDp[tid][0] + sDp[tid][1] + sDp[tid][2] + sDp[tid][3];
    sDen[tid] = 1.f / (den + 1e-6f);
  }
  __syncthreads();

  #pragma unroll
  for (int dt = 0; dt < 4; dt++)
    #pragma unroll
    for (int reg = 0; reg < 4; reg++) {
      int gi = rowW + (lane >> 4) * 4 + reg;
      int gd = dt * 16 + (lane & 15);
      float v = accO[dt][reg] * sDen[gi];
      attn_out[(size_t)(c * CS + gi) * DIMM + h * HD + gd] = __float2bfloat16(v);
    }
}

extern "C" void kernel_launch(void* const* d_in, const int* in_sizes, int n_in,
                              void* d_out, int out_size, void* d_ws, size_t ws_size,
                              hipStream_t stream) {
  (void)in_sizes; (void)n_in; (void)out_size; (void)ws_size;
  const float* x     = (const float*)d_in[0];
  const float* omega = (const float*)d_in[1];
  const float* wq    = (const float*)d_in[2];
  const float* wk    = (const float*)d_in[3];
  const float* wv    = (const float*)d_in[4];
  const float* wo    = (const float*)d_in[5];
  const float* bo    = (const float*)d_in[6];
  float* out = (float*)d_out;

  char* w = (char*)d_ws;
  _Float16* x16   = (_Float16*)(w);                  // 4 MB  [later: attn bf16 alias]
  _Float16* w16   = (_Float16*)(w + (4u  << 20));    // 6 MB
  bf16*     wo_bf = (bf16*)   (w + (10u << 20));     // 2 MB
  bf16*     vbf   = (bf16*)   (w + (12u << 20));     // 4 MB
  bf16*     phiq  = (bf16*)   (w + (16u << 20));     // 4 MB
  bf16*     phik  = (bf16*)   (w + (20u << 20));     // 4 MB
  float*    ckv   = (float*)  (w + (24u << 20));     // 8 MB (transposed [d][m])
  float*    ck    = (float*)  (w + (32u << 20));     // 128 KB
  bf16*     ckv_h = (bf16*)   (w + (34u << 20));     // 4 MB exclusive-state hi
  bf16*     ckv_l = (bf16*)   (w + (38u << 20));     // 4 MB exclusive-state lo
  bf16*     attnb = (bf16*)x16;

  cvt_all<<<6144, 256, 0, stream>>>((const float4*)x, (const float4*)wq,
                                    (const float4*)wk, (const float4*)wv,
                                    (const float4*)wo,
                                    x16, w16, wo_bf);

  gemm_qkv_phi<<<dim3(24, 16), 512, 0, stream>>>(x16, w16, omega, phiq, phik, vbf);

  chunk_sum<<<dim3(NC, NH), 256, 0, stream>>>(phik, vbf, ckv, ck);
  prefix_chunks<<<dim3(NH, 16), 256, 0, stream>>>(ckv, ck, ckv_h, ckv_l);
  attn_chunk<<<dim3(NC, NH), 256, 0, stream>>>(phiq, phik, vbf, ckv_h, ckv_l, ck, attnb);

  gemm_bf16_out<<<dim3(8, 32), 512, 0, stream>>>(attnb, wo_bf, bo, out);
}